// Round 8
// baseline (80.030 us; speedup 1.0000x reference)
//
#include <hip/hip_runtime.h>
#include <stdint.h>

// GAT layer: N=4096 nodes, IN=256, H=4 heads, F=64 out/head.
constexpr int NODES = 4096;
constexpr int KIN   = 256;
constexpr int NHEAD = 4;
constexpr int NF    = 64;
constexpr int HFQ   = 256;   // NHEAD*NF
#define L2E 1.44269504088896340736f

typedef __attribute__((ext_vector_type(8))) short short8;
typedef __attribute__((ext_vector_type(4))) float floatx4;

static __device__ __forceinline__ unsigned short f2bf(float f) {
  return __builtin_bit_cast(unsigned short, (__bf16)f);
}

// ---- kernel 1: adjacency -> transposed bitmask  +  fp32->bf16 prep ---------
// bm[jw][i] bit b = (adj[i][jw*32+b] != 0).  bm is 2 MB -> L2-resident.
__global__ __launch_bounds__(256) void pack_prep_kernel(
    const int* __restrict__ adj, unsigned* __restrict__ bm,
    const float* __restrict__ hin, const float* __restrict__ Win,
    unsigned short* __restrict__ hB, unsigned short* __restrict__ WB) {
  int tid = threadIdx.x;
  if (blockIdx.x < 2048) {
    int wv = blockIdx.x * 4 + (tid >> 6);   // 8192 waves
    int lane = tid & 63;
    int jw = wv & 127;                      // j-word (32 j's)
    int it = wv >> 7;                       // i-tile of 64
    int i = it * 64 + lane;
    const int4* p = reinterpret_cast<const int4*>(adj + (size_t)i * NODES + jw * 32);
    unsigned m = 0;
#pragma unroll
    for (int q = 0; q < 8; ++q) {
      int4 a = p[q];
      m |= (a.x != 0 ? 1u : 0u) << (q * 4);
      m |= (a.y != 0 ? 1u : 0u) << (q * 4 + 1);
      m |= (a.z != 0 ? 1u : 0u) << (q * 4 + 2);
      m |= (a.w != 0 ? 1u : 0u) << (q * 4 + 3);
    }
    bm[(size_t)jw * NODES + i] = m;
  } else {
    int idx = (blockIdx.x - 2048) * 256 + tid;  // float4 index
    const int NH4 = (NODES * KIN) / 4;          // 262144
    const int NW4 = (HFQ * KIN) / 4;            // 16384
    if (idx < NH4) {
      float4 v = reinterpret_cast<const float4*>(hin)[idx];
      ushort4 o = { f2bf(v.x), f2bf(v.y), f2bf(v.z), f2bf(v.w) };
      reinterpret_cast<ushort4*>(hB)[idx] = o;
    } else if (idx < NH4 + NW4) {
      int j = idx - NH4;
      float4 v = reinterpret_cast<const float4*>(Win)[j];
      ushort4 o = { f2bf(v.x), f2bf(v.y), f2bf(v.z), f2bf(v.w) };
      reinterpret_cast<ushort4*>(WB)[j] = o;
    }
  }
}

// ---- kernel 2: fused projection + src/dst factor tables --------------------
// grid (256 mtiles x 4 heads) = 1024 blocks; wave = one n-tile of 16 cols.
// Writes gT3 (16x16x32 A-fragment order), srcP[n][h]=(exp(s),exp(0.2s)),
// eP[h][n] = (bf16(exp(0.2d))<<16) | bf16(exp(d)).
__global__ __launch_bounds__(256) void proj_kernel(
    const unsigned short* __restrict__ hB, const unsigned short* __restrict__ WB,
    const float* __restrict__ bias, const float* __restrict__ attn_w,
    const float* __restrict__ attn_b,
    unsigned short* __restrict__ gT3, float2* __restrict__ srcP,
    unsigned* __restrict__ eP) {
  __shared__ float2 sred[4][16];
  int nt = threadIdx.x >> 6, lane = threadIdx.x & 63;
  int mt = blockIdx.x >> 2, h = blockIdx.x & 3;
  int m0 = mt * 16;
  int r = lane & 15, kg = lane >> 4;
  int col = h * NF + nt * 16 + r;
  floatx4 acc = {0.f, 0.f, 0.f, 0.f};
  const short8* Ap = reinterpret_cast<const short8*>(hB + (m0 + r) * KIN + kg * 8);
  const short8* Bp = reinterpret_cast<const short8*>(WB + col * KIN + kg * 8);
#pragma unroll
  for (int kb = 0; kb < 8; ++kb)
    acc = __builtin_amdgcn_mfma_f32_16x16x32_bf16(Ap[kb * 4], Bp[kb * 4], acc, 0, 0, 0);
  float bv = bias[col];
  float was = attn_w[nt * 16 + r], wad = attn_w[64 + nt * 16 + r];
  float ps[4], pd[4];
#pragma unroll
  for (int q = 0; q < 4; ++q) {
    int row = m0 + kg * 4 + q;            // C/D: row=(lane>>4)*4+q, col=lane&15
    float v = acc[q] + bv;
    int si = (row >> 5) * 8192 + h * 2048 + nt * 512 +
             (((row >> 3) & 3) * 16 + r) * 8 + (row & 7);
    gT3[si] = f2bf(v);
    ps[q] = v * was;
    pd[q] = v * wad;
  }
#pragma unroll
  for (int m = 8; m >= 1; m >>= 1)
#pragma unroll
    for (int q = 0; q < 4; ++q) {
      ps[q] += __shfl_xor(ps[q], m, 64);
      pd[q] += __shfl_xor(pd[q], m, 64);
    }
  if ((lane & 15) == 0)
#pragma unroll
    for (int q = 0; q < 4; ++q)
      sred[nt][kg * 4 + q] = float2{ps[q], pd[q]};
  __syncthreads();
  if (threadIdx.x < 16) {
    int row = threadIdx.x;
    float s = sred[0][row].x + sred[1][row].x + sred[2][row].x + sred[3][row].x + attn_b[0];
    float d = sred[0][row].y + sred[1][row].y + sred[2][row].y + sred[3][row].y;
    float2 sp;
    sp.x = exp2f(s * L2E);
    sp.y = exp2f(0.2f * s * L2E);
    srcP[(m0 + row) * NHEAD + h] = sp;
    float e1 = exp2f(d * L2E), e2 = exp2f(0.2f * d * L2E);
    eP[h * NODES + m0 + row] = ((unsigned)f2bf(e2) << 16) | (unsigned)f2bf(e1);
  }
}

// ---- kernel 3: denominator + fold 0.25/den into src factors ----------------
// wave per (i, h): den = sum_j adj * max(es1*e1, es2*e2); srcP2 = srcP*0.25/den.
__global__ __launch_bounds__(256) void denscale_kernel(
    const unsigned* __restrict__ bm, const unsigned* __restrict__ eP,
    const float2* __restrict__ srcP, float2* __restrict__ srcP2) {
  int wv = blockIdx.x * 4 + (threadIdx.x >> 6);
  int lane = threadIdx.x & 63;
  int h = wv & 3, i = wv >> 2;
  float2 sp = srcP[i * NHEAD + h];
  float es1 = sp.x, es2 = sp.y;
  float den = 0.f;
  const unsigned* ep = eP + h * NODES + lane;
  const unsigned* bp = bm + i;
  int sub = lane >> 5, bit = lane & 31;
  for (int k = 0; k < 64; ++k) {
    unsigned ev = ep[k * 64];                        // coalesced
    unsigned word = bp[(size_t)(k * 2 + sub) * NODES]; // broadcast (2 addrs)
    float e1f = __builtin_bit_cast(float, ev << 16);
    float e2f = __builtin_bit_cast(float, ev & 0xFFFF0000u);
    float w = fmaxf(es1 * e1f, es2 * e2f);
    den += ((word >> bit) & 1u) ? w : 0.f;
  }
#pragma unroll
  for (int m = 32; m >= 1; m >>= 1) den += __shfl_xor(den, m, 64);
  if (lane == 0) {
    float sc = 0.25f / den;
    srcP2[i * NHEAD + h] = float2{es1 * sc, es2 * sc};
  }
}

// ---- kernel 4: fused attention, 16x16x32 MFMA, fully prefetched ------------
// grid (NP, 256): blockIdx.x = j-partition (linear%8 -> one per XCD),
// blockIdx.y = i-tile of 16 rows. block 256 = 4 waves (1 head each).
// w = max(es1'*e1, es2'*e2) with 0.25/den pre-folded -> MFMA output is final.
// All loads (bm, eP, A-tiles) software-pipelined one step ahead.
// Epilogue: LDS head-reduce -> pnum[part][i][f] (heads summed).
__global__ __launch_bounds__(256, 6) void attn_kernel(
    const unsigned* __restrict__ bm, const unsigned short* __restrict__ gT3,
    const float2* __restrict__ srcP2, const unsigned* __restrict__ eP,
    float* __restrict__ pnum, int JP) {
  __shared__ float red[4][16][68];
  int tid = threadIdx.x;
  int hh = tid >> 6, lane = tid & 63;
  int il = lane & 15, kg = lane >> 4;
  int part = blockIdx.x, itile = blockIdx.y;
  int jstart = part * JP;
  int i = itile * 16 + il;

  float2 sp = srcP2[i * NHEAD + hh];
  float es1 = sp.x, es2 = sp.y;

  floatx4 acc0 = {0.f, 0.f, 0.f, 0.f};
  floatx4 acc1 = acc0, acc2 = acc0, acc3 = acc0;

  int jt0 = jstart >> 5;
  const unsigned* bmp = bm + (size_t)jt0 * NODES + i;
  const unsigned* epp = eP + hh * NODES + jstart + kg * 8;
  const unsigned short* Atp = gT3 + (size_t)jt0 * 8192 + hh * 2048 + lane * 8;

  unsigned mwd = *bmp;
  uint4 ea = *reinterpret_cast<const uint4*>(epp);
  uint4 eb = *reinterpret_cast<const uint4*>(epp + 4);
  short8 a0 = *reinterpret_cast<const short8*>(Atp);
  short8 a1 = *reinterpret_cast<const short8*>(Atp + 512);
  short8 a2 = *reinterpret_cast<const short8*>(Atp + 1024);
  short8 a3 = *reinterpret_cast<const short8*>(Atp + 1536);

  int nsteps = JP / 32;

#define STEP_BODY {                                                         \
    unsigned mb = (mwd >> (kg * 8)) & 0xFFu;                                \
    unsigned ev[8] = {ea.x, ea.y, ea.z, ea.w, eb.x, eb.y, eb.z, eb.w};      \
    short8 bfr;                                                             \
    _Pragma("unroll")                                                       \
    for (int r = 0; r < 8; ++r) {                                           \
      float e1f = __builtin_bit_cast(float, ev[r] << 16);                   \
      float e2f = __builtin_bit_cast(float, ev[r] & 0xFFFF0000u);           \
      float w = fmaxf(es1 * e1f, es2 * e2f);                                \
      w = (mb & (1u << r)) ? w : 0.f;                                       \
      bfr[r] = (short)f2bf(w);                                              \
    }                                                                       \
    acc0 = __builtin_amdgcn_mfma_f32_16x16x32_bf16(a0, bfr, acc0, 0, 0, 0); \
    acc1 = __builtin_amdgcn_mfma_f32_16x16x32_bf16(a1, bfr, acc1, 0, 0, 0); \
    acc2 = __builtin_amdgcn_mfma_f32_16x16x32_bf16(a2, bfr, acc2, 0, 0, 0); \
    acc3 = __builtin_amdgcn_mfma_f32_16x16x32_bf16(a3, bfr, acc3, 0, 0, 0); \
  }

  for (int stp = 0; stp < nsteps - 1; ++stp) {
    bmp += NODES; epp += 32; Atp += 8192;
    unsigned mwd_n = *bmp;                                    // prefetch all
    uint4 ea_n = *reinterpret_cast<const uint4*>(epp);
    uint4 eb_n = *reinterpret_cast<const uint4*>(epp + 4);
    short8 a0n = *reinterpret_cast<const short8*>(Atp);
    short8 a1n = *reinterpret_cast<const short8*>(Atp + 512);
    short8 a2n = *reinterpret_cast<const short8*>(Atp + 1024);
    short8 a3n = *reinterpret_cast<const short8*>(Atp + 1536);
    STEP_BODY;
    mwd = mwd_n; ea = ea_n; eb = eb_n;
    a0 = a0n; a1 = a1n; a2 = a2n; a3 = a3n;
  }
  STEP_BODY;                                                  // last step
#undef STEP_BODY

  // stage per-head planes: acc_ct[q] = D[c = ct*16 + kg*4 + q][i = il]
#pragma unroll
  for (int q = 0; q < 4; ++q) {
    red[hh][il][ 0 + kg * 4 + q] = acc0[q];
    red[hh][il][16 + kg * 4 + q] = acc1[q];
    red[hh][il][32 + kg * 4 + q] = acc2[q];
    red[hh][il][48 + kg * 4 + q] = acc3[q];
  }
  __syncthreads();
  // head-sum + coalesced write: thread t -> (row il2, float4 c-chunk cb)
  int il2 = tid >> 4, cb = tid & 15;
  const float4 v0 = *reinterpret_cast<const float4*>(&red[0][il2][cb * 4]);
  const float4 v1 = *reinterpret_cast<const float4*>(&red[1][il2][cb * 4]);
  const float4 v2 = *reinterpret_cast<const float4*>(&red[2][il2][cb * 4]);
  const float4 v3 = *reinterpret_cast<const float4*>(&red[3][il2][cb * 4]);
  float4 s;
  s.x = v0.x + v1.x + v2.x + v3.x;
  s.y = v0.y + v1.y + v2.y + v3.y;
  s.z = v0.z + v1.z + v2.z + v3.z;
  s.w = v0.w + v1.w + v2.w + v3.w;
  *reinterpret_cast<float4*>(pnum + (size_t)part * (NODES * NF) +
                             itile * 1024 + il2 * 64 + cb * 4) = s;
}

// ---- kernel 5: combine partials over j-partitions --------------------------
__global__ __launch_bounds__(256) void combine_kernel(
    const float4* __restrict__ pnum, float4* __restrict__ out, int NP) {
  int idx = blockIdx.x * 256 + threadIdx.x;   // float4 index, 65536 total
  float4 s = pnum[idx];
  for (int p = 1; p < NP; ++p) {
    float4 v = pnum[p * (NODES * NF / 4) + idx];
    s.x += v.x; s.y += v.y; s.z += v.z; s.w += v.w;
  }
  out[idx] = s;
}

extern "C" void kernel_launch(void* const* d_in, const int* in_sizes, int n_in,
                              void* d_out, int out_size, void* d_ws, size_t ws_size,
                              hipStream_t stream) {
  const float* hin = (const float*)d_in[0];
  const int* adj   = (const int*)d_in[1];
  const float* W   = (const float*)d_in[2];
  const float* b   = (const float*)d_in[3];
  const float* aw  = (const float*)d_in[4];
  const float* ab  = (const float*)d_in[5];
  float* out = (float*)d_out;
  char* ws = (char*)d_ws;

  unsigned short* hB  = (unsigned short*)(ws + 0x000000);  // 2 MB
  unsigned short* WB  = (unsigned short*)(ws + 0x200000);  // 128 KB
  float2* srcP        = (float2*)(ws + 0x220000);          // 128 KB
  float2* srcP2       = (float2*)(ws + 0x240000);          // 128 KB
  unsigned* eP        = (unsigned*)(ws + 0x260000);        // 64 KB
  unsigned short* gT3 = (unsigned short*)(ws + 0x400000);  // 2 MB (frag-ordered)
  unsigned* bm        = (unsigned*)(ws + 0x600000);        // 2 MB bitmask
  float* pnum         = (float*)(ws + 0x800000);           // NP * 1 MB
  const size_t base = 0x800000;

  int NP = 2;
  if (ws_size >= base + 8ull * NODES * NF * 4) NP = 8;
  else if (ws_size >= base + 4ull * NODES * NF * 4) NP = 4;
  int JP = NODES / NP;

  pack_prep_kernel<<<2048 + 1088, 256, 0, stream>>>(adj, bm, hin, W, hB, WB);
  proj_kernel<<<1024, 256, 0, stream>>>(hB, WB, b, aw, ab, gT3, srcP, eP);
  denscale_kernel<<<4096, 256, 0, stream>>>(bm, eP, srcP, srcP2);
  attn_kernel<<<dim3(NP, 256), 256, 0, stream>>>(bm, gT3, srcP2, eP, pnum, JP);
  combine_kernel<<<256, 256, 0, stream>>>((const float4*)pnum, (float4*)out, NP);
}

// Round 9
// 78.736 us; speedup vs baseline: 1.0164x; 1.0164x over previous
//
#include <hip/hip_runtime.h>
#include <stdint.h>

// GAT layer: N=4096 nodes, IN=256, H=4 heads, F=64 out/head.
constexpr int NODES = 4096;
constexpr int KIN   = 256;
constexpr int NHEAD = 4;
constexpr int NF    = 64;
constexpr int HFQ   = 256;   // NHEAD*NF
#define L2E 1.44269504088896340736f

typedef __attribute__((ext_vector_type(8))) short short8;
typedef __attribute__((ext_vector_type(4))) float floatx4;

static __device__ __forceinline__ unsigned short f2bf(float f) {
  return __builtin_bit_cast(unsigned short, (__bf16)f);
}

// ---- kernel 1: pack (adj->bitmask) OVERLAPPED with proj (h,W->gT3,tables) --
// blocks 0..2047: adjacency -> transposed bitmask bm[jw][i] (2 MB, L2-resident)
// blocks 2048..3071: projection with INLINE fp32->bf16 cvt (no prep pass):
//   grid (256 mtiles x 4 heads); wave = one n-tile of 16 cols.
//   gT3 in 16x16x32 A-fragment order; srcP[n][h]=(exp(s),exp(0.2s));
//   eP[h][n]=(bf16(exp(0.2d))<<16)|bf16(exp(d)).
// The two halves are fully independent: BW-bound pack hides compute-bound proj.
__global__ __launch_bounds__(256) void prep_kernel(
    const int* __restrict__ adj, unsigned* __restrict__ bm,
    const float* __restrict__ hin, const float* __restrict__ Win,
    const float* __restrict__ bias, const float* __restrict__ attn_w,
    const float* __restrict__ attn_b,
    unsigned short* __restrict__ gT3, float2* __restrict__ srcP,
    unsigned* __restrict__ eP) {
  __shared__ float2 sred[4][16];
  int tid = threadIdx.x;
  if (blockIdx.x < 2048) {
    int wv = blockIdx.x * 4 + (tid >> 6);   // 8192 waves
    int lane = tid & 63;
    int jw = wv & 127;                      // j-word (32 j's)
    int it = wv >> 7;                       // i-tile of 64
    int i = it * 64 + lane;
    const int4* p = reinterpret_cast<const int4*>(adj + (size_t)i * NODES + jw * 32);
    unsigned m = 0;
#pragma unroll
    for (int q = 0; q < 8; ++q) {
      int4 a = p[q];
      m |= (a.x != 0 ? 1u : 0u) << (q * 4);
      m |= (a.y != 0 ? 1u : 0u) << (q * 4 + 1);
      m |= (a.z != 0 ? 1u : 0u) << (q * 4 + 2);
      m |= (a.w != 0 ? 1u : 0u) << (q * 4 + 3);
    }
    bm[(size_t)jw * NODES + i] = m;
    return;
  }
  // ---- proj half ----
  int bid = blockIdx.x - 2048;
  int nt = tid >> 6, lane = tid & 63;
  int mt = bid >> 2, h = bid & 3;
  int m0 = mt * 16;
  int r = lane & 15, kg = lane >> 4;
  int col = h * NF + nt * 16 + r;
  floatx4 acc = {0.f, 0.f, 0.f, 0.f};
  const float* Af = hin + (m0 + r) * KIN + kg * 8;
  const float* Bf = Win + col * KIN + kg * 8;
#pragma unroll
  for (int kb = 0; kb < 8; ++kb) {
    float4 fa0 = *reinterpret_cast<const float4*>(Af + kb * 32);
    float4 fa1 = *reinterpret_cast<const float4*>(Af + kb * 32 + 4);
    float4 fb0 = *reinterpret_cast<const float4*>(Bf + kb * 32);
    float4 fb1 = *reinterpret_cast<const float4*>(Bf + kb * 32 + 4);
    short8 a, b;
    a[0] = (short)f2bf(fa0.x); a[1] = (short)f2bf(fa0.y);
    a[2] = (short)f2bf(fa0.z); a[3] = (short)f2bf(fa0.w);
    a[4] = (short)f2bf(fa1.x); a[5] = (short)f2bf(fa1.y);
    a[6] = (short)f2bf(fa1.z); a[7] = (short)f2bf(fa1.w);
    b[0] = (short)f2bf(fb0.x); b[1] = (short)f2bf(fb0.y);
    b[2] = (short)f2bf(fb0.z); b[3] = (short)f2bf(fb0.w);
    b[4] = (short)f2bf(fb1.x); b[5] = (short)f2bf(fb1.y);
    b[6] = (short)f2bf(fb1.z); b[7] = (short)f2bf(fb1.w);
    acc = __builtin_amdgcn_mfma_f32_16x16x32_bf16(a, b, acc, 0, 0, 0);
  }
  float bv = bias[col];
  float was = attn_w[nt * 16 + r], wad = attn_w[64 + nt * 16 + r];
  float ps[4], pd[4];
#pragma unroll
  for (int q = 0; q < 4; ++q) {
    int row = m0 + kg * 4 + q;            // C/D: row=(lane>>4)*4+q, col=lane&15
    float v = acc[q] + bv;
    int si = (row >> 5) * 8192 + h * 2048 + nt * 512 +
             (((row >> 3) & 3) * 16 + r) * 8 + (row & 7);
    gT3[si] = f2bf(v);
    ps[q] = v * was;
    pd[q] = v * wad;
  }
#pragma unroll
  for (int m = 8; m >= 1; m >>= 1)
#pragma unroll
    for (int q = 0; q < 4; ++q) {
      ps[q] += __shfl_xor(ps[q], m, 64);
      pd[q] += __shfl_xor(pd[q], m, 64);
    }
  if ((lane & 15) == 0)
#pragma unroll
    for (int q = 0; q < 4; ++q)
      sred[nt][kg * 4 + q] = float2{ps[q], pd[q]};
  __syncthreads();
  if (tid < 16) {
    int row = tid;
    float s = sred[0][row].x + sred[1][row].x + sred[2][row].x + sred[3][row].x + attn_b[0];
    float d = sred[0][row].y + sred[1][row].y + sred[2][row].y + sred[3][row].y;
    float2 sp;
    sp.x = exp2f(s * L2E);
    sp.y = exp2f(0.2f * s * L2E);
    srcP[(m0 + row) * NHEAD + h] = sp;
    float e1 = exp2f(d * L2E), e2 = exp2f(0.2f * d * L2E);
    eP[h * NODES + m0 + row] = ((unsigned)f2bf(e2) << 16) | (unsigned)f2bf(e1);
  }
}

// ---- kernel 2: fused attention, 16x16x32 MFMA, 8 waves/SIMD ----------------
// grid (NP, 256): blockIdx.x = j-partition (linear%8 -> one per XCD),
// blockIdx.y = i-tile of 16 rows. block 256 = 4 waves (1 head each).
// w = max(es1*e1, es2*e2)  (== exp(lrelu(s+d)), exact identity), masked by bm.
// bm/ep software-pipelined one step ahead; ones-MFMA computes denominator.
__global__ __launch_bounds__(256, 8) void attn_kernel(
    const unsigned* __restrict__ bm, const unsigned short* __restrict__ gT3,
    const float2* __restrict__ srcP, const unsigned* __restrict__ eP,
    float* __restrict__ pnum, float* __restrict__ pden, int JP) {
  int tid = threadIdx.x;
  int hh = tid >> 6, lane = tid & 63;
  int il = lane & 15, kg = lane >> 4;
  int part = blockIdx.x, itile = blockIdx.y;
  int jstart = part * JP;
  int i = itile * 16 + il;                // attention row this lane owns

  float2 sp = srcP[i * NHEAD + hh];
  float es1 = sp.x, es2 = sp.y;

  floatx4 acc0 = {0.f, 0.f, 0.f, 0.f};
  floatx4 acc1 = acc0, acc2 = acc0, acc3 = acc0, accd = acc0;

  short8 ones;
#pragma unroll
  for (int r = 0; r < 8; ++r) ones[r] = (short)0x3F80;  // bf16 1.0

  int jt0 = jstart >> 5;
  const unsigned* bmp = bm + (size_t)jt0 * NODES + i;
  const unsigned* epp = eP + hh * NODES + jstart + kg * 8;
  const unsigned short* Atp = gT3 + (size_t)jt0 * 8192 + hh * 2048 + lane * 8;

  unsigned mwd = *bmp;
  uint4 ea = *reinterpret_cast<const uint4*>(epp);
  uint4 eb = *reinterpret_cast<const uint4*>(epp + 4);

  int nsteps = JP / 32;

#define STEP_BODY {                                                         \
    unsigned mb = (mwd >> (kg * 8)) & 0xFFu;                                \
    unsigned ev[8] = {ea.x, ea.y, ea.z, ea.w, eb.x, eb.y, eb.z, eb.w};      \
    short8 bfr;                                                             \
    _Pragma("unroll")                                                       \
    for (int r = 0; r < 8; ++r) {                                           \
      float e1f = __builtin_bit_cast(float, ev[r] << 16);                   \
      float e2f = __builtin_bit_cast(float, ev[r] & 0xFFFF0000u);           \
      float w = fmaxf(es1 * e1f, es2 * e2f);                                \
      w = (mb & (1u << r)) ? w : 0.f;                                       \
      bfr[r] = (short)f2bf(w);                                              \
    }                                                                       \
    const short8 a0 = *reinterpret_cast<const short8*>(Atp);                \
    const short8 a1 = *reinterpret_cast<const short8*>(Atp + 512);          \
    const short8 a2 = *reinterpret_cast<const short8*>(Atp + 1024);         \
    const short8 a3 = *reinterpret_cast<const short8*>(Atp + 1536);         \
    acc0 = __builtin_amdgcn_mfma_f32_16x16x32_bf16(a0, bfr, acc0, 0, 0, 0); \
    acc1 = __builtin_amdgcn_mfma_f32_16x16x32_bf16(a1, bfr, acc1, 0, 0, 0); \
    acc2 = __builtin_amdgcn_mfma_f32_16x16x32_bf16(a2, bfr, acc2, 0, 0, 0); \
    acc3 = __builtin_amdgcn_mfma_f32_16x16x32_bf16(a3, bfr, acc3, 0, 0, 0); \
    accd = __builtin_amdgcn_mfma_f32_16x16x32_bf16(ones, bfr, accd, 0, 0, 0);\
  }

  for (int stp = 0; stp < nsteps - 1; ++stp) {
    unsigned mwd_n = bmp[NODES];                                  // prefetch
    uint4 ea_n = *reinterpret_cast<const uint4*>(epp + 32);
    uint4 eb_n = *reinterpret_cast<const uint4*>(epp + 36);
    STEP_BODY;
    mwd = mwd_n; ea = ea_n; eb = eb_n;
    bmp += NODES; epp += 32; Atp += 8192;
  }
  STEP_BODY;                                                      // last step
#undef STEP_BODY

  // denominator: all c-rows of accd identical; col = il
  if (kg == 0)
    pden[(size_t)part * (NODES * NHEAD) + i * NHEAD + hh] = accd[0];

  // numerator: C/D layout col=lane&15 (=i), row c_in_tile = kg*4 + q
  float* pbase = pnum + (size_t)part * (NODES * HFQ) + (size_t)i * HFQ + hh * NF;
#pragma unroll
  for (int q = 0; q < 4; ++q) {
    int c = kg * 4 + q;
    pbase[c] = acc0[q];
    pbase[16 + c] = acc1[q];
    pbase[32 + c] = acc2[q];
    pbase[48 + c] = acc3[q];
  }
}

// ---- kernel 3: combine partials, normalize, mean over heads ----------------
__global__ __launch_bounds__(256) void combine_kernel(
    const float* __restrict__ pnum, const float* __restrict__ pden,
    float* __restrict__ out, int NP) {
  int idx = blockIdx.x * 256 + threadIdx.x;
  int i = idx >> 6, f = idx & 63;
  float o = 0.f;
#pragma unroll
  for (int hh = 0; hh < NHEAD; ++hh) {
    float num = 0.f, den = 0.f;
    for (int p = 0; p < NP; ++p) {
      num += pnum[p * (NODES * HFQ) + i * HFQ + hh * NF + f];
      den += pden[p * (NODES * NHEAD) + i * NHEAD + hh];
    }
    o += num / den;
  }
  out[idx] = 0.25f * o;
}

extern "C" void kernel_launch(void* const* d_in, const int* in_sizes, int n_in,
                              void* d_out, int out_size, void* d_ws, size_t ws_size,
                              hipStream_t stream) {
  const float* hin = (const float*)d_in[0];
  const int* adj   = (const int*)d_in[1];
  const float* W   = (const float*)d_in[2];
  const float* b   = (const float*)d_in[3];
  const float* aw  = (const float*)d_in[4];
  const float* ab  = (const float*)d_in[5];
  float* out = (float*)d_out;
  char* ws = (char*)d_ws;

  unsigned short* gT3 = (unsigned short*)(ws + 0x000000);  // 2 MB (frag-ordered)
  float2* srcP        = (float2*)(ws + 0x200000);          // 128 KB
  unsigned* eP        = (unsigned*)(ws + 0x220000);        // 64 KB
  unsigned* bm        = (unsigned*)(ws + 0x240000);        // 2 MB bitmask
  float* pden         = (float*)(ws + 0x440000);           // up to 512 KB
  float* pnum         = (float*)(ws + 0x500000);           // NP * 4 MB
  const size_t base = 0x500000;

  int NP = 2;
  if (ws_size >= base + 8ull * NODES * HFQ * 4) NP = 8;
  else if (ws_size >= base + 4ull * NODES * HFQ * 4) NP = 4;
  int JP = NODES / NP;

  prep_kernel<<<3072, 256, 0, stream>>>(adj, bm, hin, W, b, aw, ab, gT3, srcP, eP);
  attn_kernel<<<dim3(NP, 256), 256, 0, stream>>>(bm, gT3, srcP, eP, pnum, pden, JP);
  combine_kernel<<<1024, 256, 0, stream>>>(pnum, pden, out, NP);
}